// Round 2
// baseline (442.350 us; speedup 1.0000x reference)
//
#include <hip/hip_runtime.h>
#include <hip/hip_bf16.h>
#include <stdint.h>

// MoE: B=4,S=2048,D=1024,E=8,TOPK=2,I=938. Sparse top-2 routing + bf16 MFMA GEMMs.
// R8: barrier-minimal 256² schedule — 2 barriers per K-tile (was 8). Mid-group
//     vmcnt(8) forces current tile's B23; group-end vmcnt(2) forces next tile's
//     A+B01 (B23 stays in flight). Waves free-run between barriers so ds_read and
//     MFMA overlap via wave drift (1 block/CU, 2 waves/SIMD). plan_kernel now
//     balances shared-tile residue assignment against per-expert routed load.

typedef __bf16 bf16_t;
typedef __bf16 bf16x8 __attribute__((ext_vector_type(8)));
typedef float  f32x4  __attribute__((ext_vector_type(4)));

#define TOKENS    8192
#define DMODEL    1024
#define NEXP      8
#define INTER     938
#define AP        1024     // padded inter dim (A cols / gemm2 K / Wd cols)
#define GUP       2048     // padded gate(1024)+up(1024) rows per expert
#define CAP_ROWS  18432    // 16384 + 8*256
#define MAX_TILES 80
#define SH_TILES  32       // 8192/256
#define BK        64

#define G1SLOTS   896      // 8 residues x 112 ranks
#define G1PER     112
#define G2SLOTS   448      // 8 residues x 56 ranks
#define G2PER     56

#define PLAN_BLOCKS 16
#define TOK_PER_PLAN (TOKENS / PLAN_BLOCKS)

// ---- async global->LDS, 16B per lane; LDS dest = wave-uniform base + lane*16 ----
__device__ __forceinline__ void async16(const bf16_t* g, bf16_t* l) {
  __builtin_amdgcn_global_load_lds(
      (__attribute__((address_space(1))) void*)(g),
      (__attribute__((address_space(3))) void*)(l),
      16, 0, 0);
}

__device__ __forceinline__ unsigned short f2bu(float f) {
  bf16_t b = (bf16_t)f;
  unsigned short u;
  __builtin_memcpy(&u, &b, 2);
  return u;
}

// ---------------- weight re-layout converts ----------------
__global__ void conv_gu_pad(const float4* __restrict__ src, ushort4* __restrict__ dst) {
  int i = blockIdx.x * 256 + threadIdx.x;
  int e = i >> 19;            // GUP*256 = 2^19
  int rem = i & 524287;
  int r = rem >> 8;
  int c4 = rem & 255;
  const float4* s = src + (size_t)e * (1876 * 256);
  float4 v = {0.f, 0.f, 0.f, 0.f};
  if (r < INTER) v = s[r * 256 + c4];
  else if (r >= 1024 && r < 1024 + INTER) v = s[(r - 86) * 256 + c4];
  ushort4 o;
  o.x = f2bu(v.x); o.y = f2bu(v.y); o.z = f2bu(v.z); o.w = f2bu(v.w);
  dst[i] = o;
}

__global__ void conv_dn_pad(const float* __restrict__ src, bf16_t* __restrict__ dst) {
  int i = blockIdx.x * 256 + threadIdx.x;
  int e = i >> 20;
  int rem = i & 1048575;
  int n = rem >> 10;
  int c = rem & 1023;
  float v = (c < INTER) ? src[(size_t)e * (1024 * INTER) + n * INTER + c] : 0.f;
  dst[i] = (bf16_t)v;
}

// ---------------- routing ----------------
__global__ void init_kernel(int* __restrict__ row_token) {
  int i = blockIdx.x * 256 + threadIdx.x;
  if (i < CAP_ROWS) row_token[i] = -1;
}

__global__ __launch_bounds__(256) void router_kernel(
    const float4* __restrict__ X4, const float4* __restrict__ GW4,
    bf16_t* __restrict__ Xb, int* __restrict__ e01, float* __restrict__ w01) {
  int token = blockIdx.x * 4 + (threadIdx.x >> 6);
  int lane = threadIdx.x & 63;
  const float4* x4 = X4 + (size_t)token * 256;

  float4 xv[4];
#pragma unroll
  for (int j = 0; j < 4; j++) xv[j] = x4[lane + 64 * j];

  ushort4* xbrow = (ushort4*)(Xb + (size_t)token * DMODEL);
#pragma unroll
  for (int j = 0; j < 4; j++) {
    ushort4 r;
    r.x = f2bu(xv[j].x); r.y = f2bu(xv[j].y);
    r.z = f2bu(xv[j].z); r.w = f2bu(xv[j].w);
    xbrow[lane + 64 * j] = r;
  }

  float acc[NEXP];
#pragma unroll
  for (int e = 0; e < NEXP; e++) {
    float a = 0.f;
#pragma unroll
    for (int j = 0; j < 4; j++) {
      float4 g = GW4[e * 256 + lane + 64 * j];
      a += xv[j].x * g.x + xv[j].y * g.y + xv[j].z * g.z + xv[j].w * g.w;
    }
    acc[e] = a;
  }
#pragma unroll
  for (int off = 32; off > 0; off >>= 1)
#pragma unroll
    for (int e = 0; e < NEXP; e++) acc[e] += __shfl_down(acc[e], off, 64);

  if (lane == 0) {
    float mx = acc[0];
#pragma unroll
    for (int e = 1; e < NEXP; e++) mx = fmaxf(mx, acc[e]);
    float p[NEXP]; float s = 0.f;
#pragma unroll
    for (int e = 0; e < NEXP; e++) { p[e] = expf(acc[e] - mx); s += p[e]; }
    int i0 = 0;
#pragma unroll
    for (int e = 1; e < NEXP; e++) if (p[e] > p[i0]) i0 = e;
    int i1 = (i0 == 0) ? 1 : 0;
#pragma unroll
    for (int e = 0; e < NEXP; e++) if (e != i1 && e != i0 && p[e] > p[i1]) i1 = e;
    float p0 = p[i0] / s, p1 = p[i1] / s;
    float inv = 1.f / (p0 + p1 + 1e-8f);
    e01[token * 2 + 0] = i0; e01[token * 2 + 1] = i1;
    w01[token * 2 + 0] = p0 * inv; w01[token * 2 + 1] = p1 * inv;
  }
}

__global__ void hist_kernel(const int* __restrict__ e01, int* __restrict__ blockCounts) {
  __shared__ int h[NEXP];
  int t = threadIdx.x;
  if (t < NEXP) h[t] = 0;
  __syncthreads();
  int base = blockIdx.x * TOK_PER_PLAN * 2;
  for (int i = t; i < TOK_PER_PLAN * 2; i += 256) atomicAdd(&h[e01[base + i]], 1);
  __syncthreads();
  if (t < NEXP) blockCounts[blockIdx.x * NEXP + t] = h[t];
}

// ---------------- plan: blockBase, tileExpert, XCD-affine balanced work lists ----------------
// 256-row tiles. gemm1: 8 f-blocks per mt. gemm2: 4 f-blocks per mt.
// Shared tiles are greedily assigned to the residue with the least total load
// (routed load = 8*tc[e] / 4*tc[e]) so per-XCD item counts equalize.
__global__ __launch_bounds__(256) void plan_kernel(
    const int* __restrict__ blockCounts, int* __restrict__ blockBase,
    int* __restrict__ tileExpert, int* __restrict__ work1, int* __restrict__ work2) {
  __shared__ int cnt[8], tc[8], tb[8], n1[8], n2[8];
  __shared__ int sres1[32], srk1[32], sres2[32], srk2[32], sc1[8], sc2[8];
  __shared__ int f1n, f2n, f1c, f2c;
  __shared__ short free1[G1SLOTS];
  __shared__ short free2[G2SLOTS];
  const int t = threadIdx.x;

  if (t < 8) {
    int s = 0;
    for (int b = 0; b < PLAN_BLOCKS; b++) s += blockCounts[b * 8 + t];
    cnt[t] = s;
  }
  if (t == 0) { f1n = 0; f2n = 0; f1c = 0; f2c = 0; }
  __syncthreads();
  if (t == 0) {
    int o = 0;
    for (int e = 0; e < 8; e++) {
      tb[e] = o;
      tc[e] = (cnt[e] + 255) / 256;
      o += tc[e];
    }
    int l1[8], l2[8];
    for (int s = 0; s < 8; s++) { l1[s] = 8 * tc[s]; l2[s] = 4 * tc[s]; sc1[s] = 0; sc2[s] = 0; }
    for (int mt = 0; mt < 32; mt++) {
      int b = 0;
      for (int s = 1; s < 8; s++) if (l1[s] < l1[b]) b = s;
      sres1[mt] = b; srk1[mt] = sc1[b]++; l1[b] += 8;
      b = 0;
      for (int s = 1; s < 8; s++) if (l2[s] < l2[b]) b = s;
      sres2[mt] = b; srk2[mt] = sc2[b]++; l2[b] += 4;
    }
    for (int s = 0; s < 8; s++) {
      n1[s] = 8 * sc1[s] + 8 * tc[s];
      n2[s] = 4 * sc2[s] + 4 * tc[s];
    }
  }
  __syncthreads();
  const int nT = tb[7] + tc[7];

  if (t < 8) {            // blockBase for scatter (rows)
    int run = tb[t] * 256;
    for (int b = 0; b < PLAN_BLOCKS; b++) {
      blockBase[b * 8 + t] = run;
      run += blockCounts[b * 8 + t];
    }
  }
  for (int i = t; i < MAX_TILES; i += 256) {   // tileExpert (256-row routed tiles)
    int e = 0;
#pragma unroll
    for (int x = 1; x < 8; x++) if (i >= tb[x]) e = x;
    tileExpert[i] = e;
  }
  for (int i = t; i < G1SLOTS; i += 256) work1[i] = -1;
  for (int i = t; i < G2SLOTS; i += 256) work2[i] = -1;
  __syncthreads();

  // own-rank fills. gemm1 shared: balanced residue, ranks 0..8*sc1-1
  for (int i = t; i < 256; i += 256) {
    int mt = i >> 3, f = i & 7;
    work1[sres1[mt] + 8 * (srk1[mt] * 8 + f)] = (mt << 4) | f;
  }
  for (int i = t; i < 8 * nT; i += 256) {      // gemm1 routed: residue = expert
    int tt = i >> 3, f = i & 7;
    int e = 0;
#pragma unroll
    for (int x = 1; x < 8; x++) if (tt >= tb[x]) e = x;
    int rk = 8 * sc1[e] + (tt - tb[e]) * 8 + f;
    if (rk < G1PER) work1[e + 8 * rk] = ((SH_TILES + tt) << 4) | f;
  }
  for (int i = t; i < 128; i += 256) {         // gemm2 shared
    int mt = i >> 2, f = i & 3;
    work2[sres2[mt] + 8 * (srk2[mt] * 4 + f)] = (mt << 4) | f;
  }
  for (int i = t; i < 4 * nT; i += 256) {      // gemm2 routed
    int tt = i >> 2, f = i & 3;
    int e = 0;
#pragma unroll
    for (int x = 1; x < 8; x++) if (tt >= tb[x]) e = x;
    int rk = 4 * sc2[e] + (tt - tb[e]) * 4 + f;
    if (rk < G2PER) work2[e + 8 * rk] = ((SH_TILES + tt) << 4) | f;
  }
  __syncthreads();

  // free slots (residues whose own list is short)
  for (int i = t; i < G1SLOTS; i += 256)
    if ((i >> 3) >= n1[i & 7]) free1[atomicAdd(&f1n, 1)] = (short)i;
  for (int i = t; i < G2SLOTS; i += 256)
    if ((i >> 3) >= n2[i & 7]) free2[atomicAdd(&f2n, 1)] = (short)i;
  __syncthreads();

  // overflow items (imbalanced experts) -> spill into free slots
  for (int i = t; i < 8 * nT; i += 256) {
    int tt = i >> 3, f = i & 7;
    int e = 0;
#pragma unroll
    for (int x = 1; x < 8; x++) if (tt >= tb[x]) e = x;
    int rk = 8 * sc1[e] + (tt - tb[e]) * 8 + f;
    if (rk >= G1PER) work1[free1[atomicAdd(&f1c, 1)]] = ((SH_TILES + tt) << 4) | f;
  }
  for (int i = t; i < 4 * nT; i += 256) {
    int tt = i >> 2, f = i & 3;
    int e = 0;
#pragma unroll
    for (int x = 1; x < 8; x++) if (tt >= tb[x]) e = x;
    int rk = 4 * sc2[e] + (tt - tb[e]) * 4 + f;
    if (rk >= G2PER) work2[free2[atomicAdd(&f2c, 1)]] = ((SH_TILES + tt) << 4) | f;
  }
}

// block-local ranks via LDS atomics; emits slotOf (token -> its 2 slot rows)
__global__ void scatter_kernel(const int* __restrict__ e01, const float* __restrict__ w01,
                               const int* __restrict__ blockBase,
                               int* __restrict__ row_token, float* __restrict__ row_weight,
                               int* __restrict__ slotOf) {
  __shared__ int cur[NEXP];
  __shared__ int base[NEXP];
  int t = threadIdx.x;
  if (t < NEXP) { cur[t] = 0; base[t] = blockBase[blockIdx.x * NEXP + t]; }
  __syncthreads();
  int tb = blockIdx.x * TOK_PER_PLAN;
  for (int i = t; i < TOK_PER_PLAN * 2; i += 256) {
    int e = e01[tb * 2 + i];
    int rank = atomicAdd(&cur[e], 1);
    int pos = base[e] + rank;
    row_token[pos] = tb + (i >> 1);
    row_weight[pos] = w01[tb * 2 + i];
    slotOf[tb * 2 + i] = pos;
  }
}

// ================= 256^2 barrier-minimal GEMM core (shared by gemm1/gemm2) =================
// 512 thr = 8 waves (4M x 2N); wave out = 64 rows x 128 cols; acc[4][8] f32x4.
// LDS: 2 slots x (A 256x64 + B 256x64) bf16 = 128KB. XOR-swizzled 16B chunks.
// B LDS rows stripe-permuted: Rl = p*64 + wn*32 + r <-> n = wn*128 + p*32 + r.
// Per K-tile group (slot S, staging t+1 -> OTH):
//   H1: ds_read av(8)+bv01(8), issue 8 gloads (A0..3,B0,B1,B2,B3), 32 MFMA
//       vmcnt(8)  -- forces tile-t B23 (2 oldest of <=10 outstanding); barrier
//   H2: ds_read bv23(8), 32 MFMA
//       vmcnt(2)  -- forces tile-(t+1) A+B01, leaves its B23 in flight; barrier
// Only 2 barriers per K-tile: waves free-run inside halves, ds_read/MFMA overlap
// via compiler lgkmcnt scheduling + wave drift. Correctness: slot S is never
// written during its group; staged quarters are ordered A0,A1,A2,A3,B0..B3 so
// the counted vmcnt retires exactly the quarters about to be read.

#define LD_AV(SLOT)                                                             \
  _Pragma("unroll") for (int mi = 0; mi < 4; ++mi) {                            \
    av[mi][0] = *(const bf16x8*)&sA[SLOT][rowA + mi*1024 + chA0];               \
    av[mi][1] = *(const bf16x8*)&sA[SLOT][rowA + mi*1024 + chA1];               \
  }

#define LD_BV(BV, SLOT, P)                                                      \
  _Pragma("unroll") for (int q = 0; q < 2; ++q) {                               \
    BV[q][0] = *(const bf16x8*)&sB[SLOT][rowB + (P)*4096 + q*1024 + chA0];      \
    BV[q][1] = *(const bf16x8*)&sB[SLOT][rowB + (P)*4096 + q*1024 + chA1];      \
  }

#define DO_MFMA(BV, P)                                                          \
  _Pragma("unroll") for (int mi = 0; mi < 4; ++mi)                              \
  _Pragma("unroll") for (int q = 0; q < 2; ++q) {                               \
    acc[mi][2*(P)+q] = __builtin_amdgcn_mfma_f32_16x16x32_bf16(                 \
        av[mi][0], BV[q][0], acc[mi][2*(P)+q], 0, 0, 0);                        \
    acc[mi][2*(P)+q] = __builtin_amdgcn_mfma_f32_16x16x32_bf16(                 \
        av[mi][1], BV[q][1], acc[mi][2*(P)+q], 0, 0, 0);                        \
  }

#define STAGE8(OTH) do {                                                        \
    async16(ap[0], &sA[OTH][0*4096 + w*512]);                                   \
    async16(ap[1], &sA[OTH][1*4096 + w*512]);                                   \
    async16(ap[2], &sA[OTH][2*4096 + w*512]);                                   \
    async16(ap[3], &sA[OTH][3*4096 + w*512]);                                   \
    async16(bp[0], &sB[OTH][0*4096 + w*512]);                                   \
    async16(bp[1], &sB[OTH][1*4096 + w*512]);                                   \
    async16(bp[2], &sB[OTH][2*4096 + w*512]);                                   \
    async16(bp[3], &sB[OTH][3*4096 + w*512]);                                   \
  } while (0)

#define GEMM_GROUP(SLOT, OTH, DO_STAGE, VM1, VM2) do {                          \
  bf16x8 av[4][2];                                                              \
  LD_AV(SLOT)                                                                   \
  {                                                                             \
    bf16x8 bv0[2][2]; LD_BV(bv0, SLOT, 0)                                       \
    if (DO_STAGE) STAGE8(OTH);                                                  \
    __builtin_amdgcn_s_setprio(1);                                              \
    DO_MFMA(bv0, 0)                                                             \
    bf16x8 bv1[2][2]; LD_BV(bv1, SLOT, 1)                                       \
    DO_MFMA(bv1, 1)                                                             \
    __builtin_amdgcn_s_setprio(0);                                              \
  }                                                                             \
  asm volatile("s_waitcnt vmcnt(" #VM1 ")" ::: "memory");                       \
  __builtin_amdgcn_s_barrier();                                                 \
  {                                                                             \
    bf16x8 bv2[2][2]; LD_BV(bv2, SLOT, 2)                                       \
    __builtin_amdgcn_s_setprio(1);                                              \
    DO_MFMA(bv2, 2)                                                             \
    bf16x8 bv3[2][2]; LD_BV(bv3, SLOT, 3)                                       \
    DO_MFMA(bv3, 3)                                                             \
    __builtin_amdgcn_s_setprio(0);                                              \
  }                                                                             \
  asm volatile("s_waitcnt vmcnt(" #VM2 ")" ::: "memory");                       \
  __builtin_amdgcn_s_barrier();                                                 \
  if (DO_STAGE) {                                                               \
    _Pragma("unroll") for (int a_ = 0; a_ < 4; ++a_) {                          \
      ap[a_] += BK; bp[a_] += BK; }                                             \
  }                                                                             \
} while (0)

// ---------------- GEMM1 (fused shared+routed): A[M,1024] = swiglu(X @ Wgu^T) ----------------
// item = (mt<<4)|f0, f0 in 0..7. N-tile 256 = 128 gate + 128 up cols interleaved at
// 16-col granularity (pairs stay within one wave); inter cols f0*128 .. f0*128+127.
__global__ __launch_bounds__(512, 2) void gemm1_fused(
    const bf16_t* __restrict__ Xb, const bf16_t* __restrict__ WS,
    const bf16_t* __restrict__ WE, bf16_t* __restrict__ As, bf16_t* __restrict__ Ar,
    const int* __restrict__ row_token, const int* __restrict__ tileExpert,
    const int* __restrict__ work1) {
  const int item = work1[blockIdx.x];
  if (item < 0) return;
  const int mt = item >> 4;
  const int f0 = item & 15;

  const bf16_t* W; bf16_t* Aout; int m0; const int* rtok = nullptr;
  if (mt < SH_TILES) {
    m0 = mt * 256; W = WS; Aout = As;
  } else {
    int rt = mt - SH_TILES;
    m0 = rt * 256; W = WE + (size_t)tileExpert[rt] * (GUP * DMODEL);
    Aout = Ar; rtok = row_token;
  }

  __shared__ bf16_t sA[2][16384];   // 64KB
  __shared__ bf16_t sB[2][16384];   // 64KB

  const int tid = threadIdx.x;
  const int w = tid >> 6, lane = tid & 63;
  const int wm = w >> 1, wn = w & 1;
  const int lr = lane & 15, quad = lane >> 4;

  // staging pointers (pre-swizzled global sources; linear LDS dests)
  const bf16_t* ap[4]; const bf16_t* bp[4];
#pragma unroll
  for (int a = 0; a < 4; a++) {
    int row = a * 64 + (tid >> 3);
    int ch = (tid & 7) ^ (row & 7);
    int tok = m0 + row;
    if (rtok) { int tt = rtok[tok]; tok = (tt < 0) ? 0 : tt; }
    ap[a] = Xb + (size_t)tok * DMODEL + ch * 8;
    // B: LDS row Rl = row; decode stripe-permuted logical col, then gate/up interleave
    int p = row >> 6, wnn = (row >> 5) & 1, r = row & 31;
    int n = wnn * 128 + p * 32 + r;
    int ni = (n >> 4) & 7;
    int wrow = ((ni & 1) ? 1024 : 0) + f0 * 128 + (wnn * 4 + (ni >> 1)) * 16 + (n & 15);
    bp[a] = W + (size_t)wrow * DMODEL + ch * 8;
  }

  const int chA0 = (quad ^ (lr & 7)) * 8;
  const int chA1 = ((4 + quad) ^ (lr & 7)) * 8;
  const int rowA = (wm * 64 + lr) * 64;
  const int rowB = (wn * 32 + lr) * 64;

  f32x4 acc[4][8];
#pragma unroll
  for (int mi = 0; mi < 4; mi++)
#pragma unroll
    for (int ni = 0; ni < 8; ni++) acc[mi][ni] = (f32x4){0.f, 0.f, 0.f, 0.f};

  // prologue: stage K-tile 0 into slot 0 (order A0..3,B0..3), force A+B01
#pragma unroll
  for (int a = 0; a < 4; a++) async16(ap[a], &sA[0][a * 4096 + w * 512]);
#pragma unroll
  for (int a = 0; a < 4; a++) async16(bp[a], &sB[0][a * 4096 + w * 512]);
#pragma unroll
  for (int a = 0; a < 4; a++) { ap[a] += BK; bp[a] += BK; }
  asm volatile("s_waitcnt vmcnt(2)" ::: "memory");
  __builtin_amdgcn_s_barrier();

#pragma unroll 1
  for (int it = 0; it < 7; ++it) {
    GEMM_GROUP(0, 1, true, 8, 2);
    GEMM_GROUP(1, 0, true, 8, 2);
  }
  GEMM_GROUP(0, 1, true, 8, 2);    // kt=14, stages tile 15
  GEMM_GROUP(1, 0, false, 0, 0);   // kt=15

  // epilogue: pair gate(ni=2j) with up(ni=2j+1); zero-padded weights give exact 0
  // for inter cols >= 938 (required: gemm2 runs K=1024 over these).
#pragma unroll
  for (int mi = 0; mi < 4; mi++)
#pragma unroll
    for (int j = 0; j < 4; j++)
#pragma unroll
      for (int r = 0; r < 4; r++) {
        int row = m0 + wm * 64 + mi * 16 + quad * 4 + r;
        int col = f0 * 128 + (wn * 4 + j) * 16 + lr;
        float g = acc[mi][2 * j][r], u = acc[mi][2 * j + 1][r];
        float v = (g / (1.f + __expf(-g))) * u;
        Aout[(size_t)row * AP + col] = (bf16_t)v;
      }
}

// ---------------- GEMM2 (fused shared+routed): Out[M,1024] = A @ Wd^T, K=1024 ----------------
// item = (mt<<4)|f, f in 0..3, n0 = f*256.
__global__ __launch_bounds__(512, 2) void gemm2_fused(
    const bf16_t* __restrict__ As, const bf16_t* __restrict__ Ar,
    const bf16_t* __restrict__ WS, const bf16_t* __restrict__ WE,
    float* __restrict__ Out, bf16_t* __restrict__ Yr,
    const float* __restrict__ row_weight, const int* __restrict__ tileExpert,
    const int* __restrict__ work2) {
  const int item = work2[blockIdx.x];
  if (item < 0) return;
  const int mt = item >> 4;
  const int n0 = (item & 15) * 256;

  const bf16_t* A; const bf16_t* W; int m0; bool routed;
  if (mt < SH_TILES) {
    routed = false; m0 = mt * 256; A = As; W = WS;
  } else {
    int rt = mt - SH_TILES;
    routed = true; m0 = rt * 256; A = Ar;
    W = WE + (size_t)tileExpert[rt] * (DMODEL * AP);
  }

  __shared__ bf16_t sA[2][16384];
  __shared__ bf16_t sB[2][16384];

  const int tid = threadIdx.x;
  const int w = tid >> 6, lane = tid & 63;
  const int wm = w >> 1, wn = w & 1;
  const int lr = lane & 15, quad = lane >> 4;

  const bf16_t* ap[4]; const bf16_t* bp[4];
#pragma unroll
  for (int a = 0; a < 4; a++) {
    int row = a * 64 + (tid >> 3);
    int ch = (tid & 7) ^ (row & 7);
    ap[a] = A + (size_t)(m0 + row) * AP + ch * 8;
    int p = row >> 6, wnn = (row >> 5) & 1, r = row & 31;
    int n = wnn * 128 + p * 32 + r;
    bp[a] = W + (size_t)(n0 + n) * AP + ch * 8;
  }

  const int chA0 = (quad ^ (lr & 7)) * 8;
  const int chA1 = ((4 + quad) ^ (lr & 7)) * 8;
  const int rowA = (wm * 64 + lr) * 64;
  const int rowB = (wn * 32 + lr) * 64;

  f32x4 acc[4][8];
#pragma unroll
  for (int mi = 0; mi < 4; mi++)
#pragma unroll
    for (int ni = 0; ni < 8; ni++) acc[mi][ni] = (f32x4){0.f, 0.f, 0.f, 0.f};

#pragma unroll
  for (int a = 0; a < 4; a++) async16(ap[a], &sA[0][a * 4096 + w * 512]);
#pragma unroll
  for (int a = 0; a < 4; a++) async16(bp[a], &sB[0][a * 4096 + w * 512]);
#pragma unroll
  for (int a = 0; a < 4; a++) { ap[a] += BK; bp[a] += BK; }
  asm volatile("s_waitcnt vmcnt(2)" ::: "memory");
  __builtin_amdgcn_s_barrier();

#pragma unroll 1
  for (int it = 0; it < 7; ++it) {
    GEMM_GROUP(0, 1, true, 8, 2);
    GEMM_GROUP(1, 0, true, 8, 2);
  }
  GEMM_GROUP(0, 1, true, 8, 2);
  GEMM_GROUP(1, 0, false, 0, 0);

#pragma unroll
  for (int mi = 0; mi < 4; mi++) {
#pragma unroll
    for (int r = 0; r < 4; r++) {
      int row = m0 + wm * 64 + mi * 16 + quad * 4 + r;
      float rw = routed ? row_weight[row] : 0.f;
#pragma unroll
      for (int ni = 0; ni < 8; ni++) {
        int col = n0 + wn * 128 + ni * 16 + lr;
        float v = acc[mi][ni][r];
        if (!routed) Out[(size_t)row * DMODEL + col] = v;
        else         Yr[(size_t)row * DMODEL + col] = (bf16_t)(rw * v);
      }
    }
  }
}

// ---------------- combine: Out[t] += Yr[slot0(t)] + Yr[slot1(t)] ----------------
__global__ __launch_bounds__(256) void combine_kernel(
    float4* __restrict__ Out4, const ushort4* __restrict__ Yr4,
    const int* __restrict__ slotOf) {
  int t = blockIdx.x;
  int c = threadIdx.x;
  int s0 = slotOf[t * 2 + 0];
  int s1 = slotOf[t * 2 + 1];
  float4 o = Out4[t * 256 + c];
  ushort4 a = Yr4[(size_t)s0 * 256 + c];
  ushort4 b = Yr4[(size_t)s1 * 256 + c];
  union { unsigned int u; float f; } cv;
  auto b2f = [&](unsigned short x) { cv.u = ((unsigned int)x) << 16; return cv.f; };
  o.x += b2f(a.x) + b2f(b.x);
  o.y += b2f(a.y) + b2f(b.y);
  o.z += b2f(a.z) + b2f(b.z);
  o.w += b2f(a.w) + b2f(b.w);
  Out4[t * 256 + c] = o;
}

// ---------------- launch ----------------
extern "C" void kernel_launch(void* const* d_in, const int* in_sizes, int n_in,
                              void* d_out, int out_size, void* d_ws, size_t ws_size,
                              hipStream_t stream) {
  const float* X   = (const float*)d_in[0];
  const float* GW  = (const float*)d_in[1];
  const float* SGU = (const float*)d_in[2];
  const float* SD  = (const float*)d_in[3];
  const float* EGU = (const float*)d_in[4];
  const float* ED  = (const float*)d_in[5];
  float* Out = (float*)d_out;

  char* ws = (char*)d_ws;
  size_t o = 0;
  auto alloc = [&](size_t b) -> char* {
    char* p = ws + o;
    o = (o + b + 255) & ~(size_t)255;
    return p;
  };
  bf16_t* Xb    = (bf16_t*)alloc((size_t)TOKENS * DMODEL * 2);          // 16.8 MB
  bf16_t* WguSP = (bf16_t*)alloc((size_t)GUP * DMODEL * 2);             // 4.2 MB
  bf16_t* WdSP  = (bf16_t*)alloc((size_t)DMODEL * AP * 2);              // 2.1 MB
  bf16_t* WguEP = (bf16_t*)alloc((size_t)NEXP * GUP * DMODEL * 2);      // 33.6 MB
  bf16_t* WdEP  = (bf16_t*)alloc((size_t)NEXP * DMODEL * AP * 2);       // 16.8 MB
  bf16_t* As    = (bf16_t*)alloc((size_t)TOKENS * AP * 2);              // 16.8 MB
  bf16_t* Ar    = (bf16_t*)alloc((size_t)CAP_ROWS * AP * 2);            // 37.7 MB
  bf16_t* Yr    = (bf16_t*)alloc((size_t)CAP_ROWS * DMODEL * 2);        // 37.7 MB
  int*    e01    = (int*)alloc(TOKENS * 2 * 4);
  float*  w01    = (float*)alloc(TOKENS * 2 * 4);
  int*    slotOf = (int*)alloc(TOKENS * 2 * 4);
  int*    blkCnt = (int*)alloc(PLAN_BLOCKS * NEXP * 4);
  int*    blkBas = (int*)alloc(PLAN_BLOCKS * NEXP * 4);
  int*    tileEx = (int*)alloc(MAX_TILES * 4);
  int*    work1  = (int*)alloc(G1SLOTS * 4);
  int*    work2  = (int*)alloc(G2SLOTS * 4);
  int*    rowTok = (int*)alloc(CAP_ROWS * 4);
  float*  rowW   = (float*)alloc(CAP_ROWS * 4);
  (void)ws_size; (void)in_sizes; (void)n_in; (void)out_size;

  // weight re-layout (padded)
  conv_gu_pad<<<2048, 256, 0, stream>>>((const float4*)SGU, (ushort4*)WguSP);
  conv_gu_pad<<<NEXP * 2048, 256, 0, stream>>>((const float4*)EGU, (ushort4*)WguEP);
  conv_dn_pad<<<4096, 256, 0, stream>>>(SD, WdSP);
  conv_dn_pad<<<NEXP * 4096, 256, 0, stream>>>(ED, WdEP);

  // routing
  init_kernel<<<(CAP_ROWS + 255) / 256, 256, 0, stream>>>(rowTok);
  router_kernel<<<TOKENS / 4, 256, 0, stream>>>(
      (const float4*)X, (const float4*)GW, Xb, e01, w01);
  hist_kernel<<<PLAN_BLOCKS, 256, 0, stream>>>(e01, blkCnt);
  plan_kernel<<<1, 256, 0, stream>>>(blkCnt, blkBas, tileEx, work1, work2);
  scatter_kernel<<<PLAN_BLOCKS, 256, 0, stream>>>(e01, w01, blkBas, rowTok, rowW, slotOf);

  // GEMMs: 256^2 barrier-minimal pipelined, work-list driven with expert<->XCD affinity
  gemm1_fused<<<G1SLOTS, 512, 0, stream>>>(
      Xb, WguSP, WguEP, As, Ar, rowTok, tileEx, work1);
  gemm2_fused<<<G2SLOTS, 512, 0, stream>>>(
      As, Ar, WdSP, WdEP, Out, Yr, rowW, tileEx, work2);
  combine_kernel<<<TOKENS, 256, 0, stream>>>((float4*)Out, (const ushort4*)Yr, slotOf);
}

// Round 3
// 437.175 us; speedup vs baseline: 1.0118x; 1.0118x over previous
//
#include <hip/hip_runtime.h>
#include <hip/hip_bf16.h>
#include <stdint.h>

// MoE: B=4,S=2048,D=1024,E=8,TOPK=2,I=938. Sparse top-2 routing + bf16 MFMA GEMMs.
// R9: faithful m201 8-phase port. 8 waves 2Mx4N (wave-tile 128x64, acc[8][4]).
//     Per K-tile: 4 C-quadrant phases (mh,nh), each {ds_read 12-or-4 ∥ stage 1
//     half-tile (2 gloads) → barrier → lgkmcnt(0) → setprio(1) 16 MFMA → barrier}.
//     Counted vmcnt: (4)@ph1 forces tile's B1-half, (2)@boundary leaves next B1
//     in flight — never 0 in steady state. B LDS rows permuted so nh-halves are
//     contiguous staged units. plan_kernel = R7 static XCD-affine (R8 greedy reverted).

typedef __bf16 bf16_t;
typedef __bf16 bf16x8 __attribute__((ext_vector_type(8)));
typedef float  f32x4  __attribute__((ext_vector_type(4)));

#define TOKENS    8192
#define DMODEL    1024
#define NEXP      8
#define INTER     938
#define AP        1024     // padded inter dim (A cols / gemm2 K / Wd cols)
#define GUP       2048     // padded gate(1024)+up(1024) rows per expert
#define CAP_ROWS  18432    // 16384 + 8*256
#define MAX_TILES 80
#define SH_TILES  32       // 8192/256
#define BK        64

#define G1SLOTS   896      // 8 residues x 112 ranks
#define G1PER     112
#define G2SLOTS   448      // 8 residues x 56 ranks
#define G2PER     56

#define PLAN_BLOCKS 16
#define TOK_PER_PLAN (TOKENS / PLAN_BLOCKS)

// ---- async global->LDS, 16B per lane; LDS dest = wave-uniform base + lane*16 ----
__device__ __forceinline__ void async16(const bf16_t* g, bf16_t* l) {
  __builtin_amdgcn_global_load_lds(
      (__attribute__((address_space(1))) void*)(g),
      (__attribute__((address_space(3))) void*)(l),
      16, 0, 0);
}

__device__ __forceinline__ unsigned short f2bu(float f) {
  bf16_t b = (bf16_t)f;
  unsigned short u;
  __builtin_memcpy(&u, &b, 2);
  return u;
}

// ---------------- weight re-layout converts ----------------
__global__ void conv_gu_pad(const float4* __restrict__ src, ushort4* __restrict__ dst) {
  int i = blockIdx.x * 256 + threadIdx.x;
  int e = i >> 19;            // GUP*256 = 2^19
  int rem = i & 524287;
  int r = rem >> 8;
  int c4 = rem & 255;
  const float4* s = src + (size_t)e * (1876 * 256);
  float4 v = {0.f, 0.f, 0.f, 0.f};
  if (r < INTER) v = s[r * 256 + c4];
  else if (r >= 1024 && r < 1024 + INTER) v = s[(r - 86) * 256 + c4];
  ushort4 o;
  o.x = f2bu(v.x); o.y = f2bu(v.y); o.z = f2bu(v.z); o.w = f2bu(v.w);
  dst[i] = o;
}

__global__ void conv_dn_pad(const float* __restrict__ src, bf16_t* __restrict__ dst) {
  int i = blockIdx.x * 256 + threadIdx.x;
  int e = i >> 20;
  int rem = i & 1048575;
  int n = rem >> 10;
  int c = rem & 1023;
  float v = (c < INTER) ? src[(size_t)e * (1024 * INTER) + n * INTER + c] : 0.f;
  dst[i] = (bf16_t)v;
}

// ---------------- routing ----------------
__global__ void init_kernel(int* __restrict__ row_token) {
  int i = blockIdx.x * 256 + threadIdx.x;
  if (i < CAP_ROWS) row_token[i] = -1;
}

__global__ __launch_bounds__(256) void router_kernel(
    const float4* __restrict__ X4, const float4* __restrict__ GW4,
    bf16_t* __restrict__ Xb, int* __restrict__ e01, float* __restrict__ w01) {
  int token = blockIdx.x * 4 + (threadIdx.x >> 6);
  int lane = threadIdx.x & 63;
  const float4* x4 = X4 + (size_t)token * 256;

  float4 xv[4];
#pragma unroll
  for (int j = 0; j < 4; j++) xv[j] = x4[lane + 64 * j];

  ushort4* xbrow = (ushort4*)(Xb + (size_t)token * DMODEL);
#pragma unroll
  for (int j = 0; j < 4; j++) {
    ushort4 r;
    r.x = f2bu(xv[j].x); r.y = f2bu(xv[j].y);
    r.z = f2bu(xv[j].z); r.w = f2bu(xv[j].w);
    xbrow[lane + 64 * j] = r;
  }

  float acc[NEXP];
#pragma unroll
  for (int e = 0; e < NEXP; e++) {
    float a = 0.f;
#pragma unroll
    for (int j = 0; j < 4; j++) {
      float4 g = GW4[e * 256 + lane + 64 * j];
      a += xv[j].x * g.x + xv[j].y * g.y + xv[j].z * g.z + xv[j].w * g.w;
    }
    acc[e] = a;
  }
#pragma unroll
  for (int off = 32; off > 0; off >>= 1)
#pragma unroll
    for (int e = 0; e < NEXP; e++) acc[e] += __shfl_down(acc[e], off, 64);

  if (lane == 0) {
    float mx = acc[0];
#pragma unroll
    for (int e = 1; e < NEXP; e++) mx = fmaxf(mx, acc[e]);
    float p[NEXP]; float s = 0.f;
#pragma unroll
    for (int e = 0; e < NEXP; e++) { p[e] = expf(acc[e] - mx); s += p[e]; }
    int i0 = 0;
#pragma unroll
    for (int e = 1; e < NEXP; e++) if (p[e] > p[i0]) i0 = e;
    int i1 = (i0 == 0) ? 1 : 0;
#pragma unroll
    for (int e = 0; e < NEXP; e++) if (e != i1 && e != i0 && p[e] > p[i1]) i1 = e;
    float p0 = p[i0] / s, p1 = p[i1] / s;
    float inv = 1.f / (p0 + p1 + 1e-8f);
    e01[token * 2 + 0] = i0; e01[token * 2 + 1] = i1;
    w01[token * 2 + 0] = p0 * inv; w01[token * 2 + 1] = p1 * inv;
  }
}

__global__ void hist_kernel(const int* __restrict__ e01, int* __restrict__ blockCounts) {
  __shared__ int h[NEXP];
  int t = threadIdx.x;
  if (t < NEXP) h[t] = 0;
  __syncthreads();
  int base = blockIdx.x * TOK_PER_PLAN * 2;
  for (int i = t; i < TOK_PER_PLAN * 2; i += 256) atomicAdd(&h[e01[base + i]], 1);
  __syncthreads();
  if (t < NEXP) blockCounts[blockIdx.x * NEXP + t] = h[t];
}

// ---------------- plan: blockBase, tileExpert, XCD-affine work lists (R7 static) ----------------
__global__ __launch_bounds__(256) void plan_kernel(
    const int* __restrict__ blockCounts, int* __restrict__ blockBase,
    int* __restrict__ tileExpert, int* __restrict__ work1, int* __restrict__ work2) {
  __shared__ int cnt[8], tc[8], tb[8], n1[8], n2[8];
  __shared__ int f1n, f2n, f1c, f2c;
  __shared__ short free1[G1SLOTS];
  __shared__ short free2[G2SLOTS];
  const int t = threadIdx.x;

  if (t < 8) {
    int s = 0;
    for (int b = 0; b < PLAN_BLOCKS; b++) s += blockCounts[b * 8 + t];
    cnt[t] = s;
  }
  if (t == 0) { f1n = 0; f2n = 0; f1c = 0; f2c = 0; }
  __syncthreads();
  if (t == 0) {
    int o = 0;
    for (int e = 0; e < 8; e++) {
      tb[e] = o;
      tc[e] = (cnt[e] + 255) / 256;
      o += tc[e];
    }
    for (int s = 0; s < 8; s++) { n1[s] = 32 + 8 * tc[s]; n2[s] = 16 + 4 * tc[s]; }
  }
  __syncthreads();
  const int nT = tb[7] + tc[7];

  if (t < 8) {            // blockBase for scatter (rows)
    int run = tb[t] * 256;
    for (int b = 0; b < PLAN_BLOCKS; b++) {
      blockBase[b * 8 + t] = run;
      run += blockCounts[b * 8 + t];
    }
  }
  for (int i = t; i < MAX_TILES; i += 256) {   // tileExpert (256-row routed tiles)
    int e = 0;
#pragma unroll
    for (int x = 1; x < 8; x++) if (i >= tb[x]) e = x;
    tileExpert[i] = e;
  }
  for (int i = t; i < G1SLOTS; i += 256) work1[i] = -1;
  for (int i = t; i < G2SLOTS; i += 256) work2[i] = -1;
  __syncthreads();

  // own-rank fills. gemm1 shared: mt 0..31, f 0..7 -> residue mt&7, rank (mt>>3)*8+f
  for (int i = t; i < 256; i += 256) {
    int mt = i >> 3, f = i & 7;
    work1[(mt & 7) + 8 * ((mt >> 3) * 8 + f)] = (mt << 4) | f;
  }
  for (int i = t; i < 8 * nT; i += 256) {      // gemm1 routed: residue = expert
    int tt = i >> 3, f = i & 7;
    int e = 0;
#pragma unroll
    for (int x = 1; x < 8; x++) if (tt >= tb[x]) e = x;
    int rk = 32 + (tt - tb[e]) * 8 + f;
    if (rk < G1PER) work1[e + 8 * rk] = ((SH_TILES + tt) << 4) | f;
  }
  for (int i = t; i < 128; i += 256) {         // gemm2 shared: mt 0..31, f 0..3
    int mt = i >> 2, f = i & 3;
    work2[(mt & 7) + 8 * ((mt >> 3) * 4 + f)] = (mt << 4) | f;
  }
  for (int i = t; i < 4 * nT; i += 256) {      // gemm2 routed
    int tt = i >> 2, f = i & 3;
    int e = 0;
#pragma unroll
    for (int x = 1; x < 8; x++) if (tt >= tb[x]) e = x;
    int rk = 16 + (tt - tb[e]) * 4 + f;
    if (rk < G2PER) work2[e + 8 * rk] = ((SH_TILES + tt) << 4) | f;
  }
  __syncthreads();

  // free slots (residues whose own list is short)
  for (int i = t; i < G1SLOTS; i += 256)
    if ((i >> 3) >= n1[i & 7]) free1[atomicAdd(&f1n, 1)] = (short)i;
  for (int i = t; i < G2SLOTS; i += 256)
    if ((i >> 3) >= n2[i & 7]) free2[atomicAdd(&f2n, 1)] = (short)i;
  __syncthreads();

  // overflow items (imbalanced experts) -> spill into free slots
  for (int i = t; i < 8 * nT; i += 256) {
    int tt = i >> 3, f = i & 7;
    int e = 0;
#pragma unroll
    for (int x = 1; x < 8; x++) if (tt >= tb[x]) e = x;
    int rk = 32 + (tt - tb[e]) * 8 + f;
    if (rk >= G1PER) work1[free1[atomicAdd(&f1c, 1)]] = ((SH_TILES + tt) << 4) | f;
  }
  for (int i = t; i < 4 * nT; i += 256) {
    int tt = i >> 2, f = i & 3;
    int e = 0;
#pragma unroll
    for (int x = 1; x < 8; x++) if (tt >= tb[x]) e = x;
    int rk = 16 + (tt - tb[e]) * 4 + f;
    if (rk >= G2PER) work2[free2[atomicAdd(&f2c, 1)]] = ((SH_TILES + tt) << 4) | f;
  }
}

// block-local ranks via LDS atomics; emits slotOf (token -> its 2 slot rows)
__global__ void scatter_kernel(const int* __restrict__ e01, const float* __restrict__ w01,
                               const int* __restrict__ blockBase,
                               int* __restrict__ row_token, float* __restrict__ row_weight,
                               int* __restrict__ slotOf) {
  __shared__ int cur[NEXP];
  __shared__ int base[NEXP];
  int t = threadIdx.x;
  if (t < NEXP) { cur[t] = 0; base[t] = blockBase[blockIdx.x * NEXP + t]; }
  __syncthreads();
  int tb = blockIdx.x * TOK_PER_PLAN;
  for (int i = t; i < TOK_PER_PLAN * 2; i += 256) {
    int e = e01[tb * 2 + i];
    int rank = atomicAdd(&cur[e], 1);
    int pos = base[e] + rank;
    row_token[pos] = tb + (i >> 1);
    row_weight[pos] = w01[tb * 2 + i];
    slotOf[tb * 2 + i] = pos;
  }
}

// ================= 256^2 8-phase GEMM core (m201-faithful) =================
// 512 thr = 8 waves (2M x 4N): wm=w>>2, wn=w&3. Wave-tile 128M x 64N; acc[8][4].
// LDS: 2 slots x (A 256x64 + B 256x64) bf16 = 128KB, XOR-swizzled 16B chunks.
// B rows permuted: Rl = nh*128 + wn*32 + nf*16 + lr  <->  n = wn*64 + nh*32 + r,
// so nh-halves are contiguous 128-row staged units.
// Per K-tile: 4 C-quadrant phases (mh,nh) = (0,0),(0,1),(1,0),(1,1); each phase:
//   {ds_read av(8, mh-change only)+bv(4) ∥ stage 1 half (2 gloads) → barrier →
//    lgkmcnt(0) → setprio(1) 16 MFMA setprio(0) → barrier}
// Waits (ledger, 8 stage-instr/K-tile, entry state = [B1(t)]):
//   ph1: after staging A1' → 6 outstanding, vmcnt(4) forces B1(t), leaves A0',A1'
//   ph3 end: 8 outstanding, vmcnt(2) forces A0',A1',B0', leaves B1' = entry state.

#define RD_AV(S, MH)                                                            \
  _Pragma("unroll") for (int mi = 0; mi < 4; ++mi) {                            \
    av[mi][0] = *(const bf16x8*)&sA[S][rowA + (MH)*4096 + mi*1024 + chA0];      \
    av[mi][1] = *(const bf16x8*)&sA[S][rowA + (MH)*4096 + mi*1024 + chA1];      \
  }

#define RD_BV(S, NH)                                                            \
  _Pragma("unroll") for (int nf = 0; nf < 2; ++nf) {                            \
    bv[nf][0] = *(const bf16x8*)&sB[S][rowB + (NH)*8192 + nf*1024 + chA0];      \
    bv[nf][1] = *(const bf16x8*)&sB[S][rowB + (NH)*8192 + nf*1024 + chA1];      \
  }

#define MM(MH, NH)                                                              \
  _Pragma("unroll") for (int nf = 0; nf < 2; ++nf)                              \
  _Pragma("unroll") for (int mi = 0; mi < 4; ++mi) {                            \
    acc[(MH)*4+mi][(NH)*2+nf] = __builtin_amdgcn_mfma_f32_16x16x32_bf16(        \
        av[mi][0], bv[nf][0], acc[(MH)*4+mi][(NH)*2+nf], 0, 0, 0);              \
    acc[(MH)*4+mi][(NH)*2+nf] = __builtin_amdgcn_mfma_f32_16x16x32_bf16(        \
        av[mi][1], bv[nf][1], acc[(MH)*4+mi][(NH)*2+nf], 0, 0, 0);              \
  }

#define PH_TAIL                                                                 \
  __builtin_amdgcn_s_barrier();                                                 \
  asm volatile("s_waitcnt lgkmcnt(0)" ::: "memory");

#define GROUP8(S, OTH, DO_STAGE, VM1, VMEND) do {                               \
  bf16x8 av[4][2]; bf16x8 bv[2][2];                                             \
  /* ph0: (mh0,nh0), stage A0' */                                               \
  RD_AV(S, 0) RD_BV(S, 0)                                                       \
  if (DO_STAGE) { async16(ap[0], &sA[OTH][0*4096 + w*512]);                     \
                  async16(ap[1], &sA[OTH][1*4096 + w*512]); }                   \
  PH_TAIL                                                                       \
  __builtin_amdgcn_s_setprio(1); MM(0, 0) __builtin_amdgcn_s_setprio(0);        \
  __builtin_amdgcn_s_barrier();                                                 \
  /* ph1: (mh0,nh1), stage A1', force B1(t) */                                  \
  if (DO_STAGE) { async16(ap[2], &sA[OTH][2*4096 + w*512]);                     \
                  async16(ap[3], &sA[OTH][3*4096 + w*512]); }                   \
  asm volatile("s_waitcnt vmcnt(" #VM1 ")" ::: "memory");                       \
  RD_BV(S, 1)                                                                   \
  PH_TAIL                                                                       \
  __builtin_amdgcn_s_setprio(1); MM(0, 1) __builtin_amdgcn_s_setprio(0);        \
  __builtin_amdgcn_s_barrier();                                                 \
  /* ph2: (mh1,nh0), stage B0' */                                               \
  RD_AV(S, 1) RD_BV(S, 0)                                                       \
  if (DO_STAGE) { async16(bp[0], &sB[OTH][0*4096 + w*512]);                     \
                  async16(bp[1], &sB[OTH][1*4096 + w*512]); }                   \
  PH_TAIL                                                                       \
  __builtin_amdgcn_s_setprio(1); MM(1, 0) __builtin_amdgcn_s_setprio(0);        \
  __builtin_amdgcn_s_barrier();                                                 \
  /* ph3: (mh1,nh1), stage B1', boundary vmcnt */                               \
  RD_BV(S, 1)                                                                   \
  if (DO_STAGE) { async16(bp[2], &sB[OTH][2*4096 + w*512]);                     \
                  async16(bp[3], &sB[OTH][3*4096 + w*512]); }                   \
  PH_TAIL                                                                       \
  __builtin_amdgcn_s_setprio(1); MM(1, 1) __builtin_amdgcn_s_setprio(0);        \
  asm volatile("s_waitcnt vmcnt(" #VMEND ")" ::: "memory");                     \
  __builtin_amdgcn_s_barrier();                                                 \
  if (DO_STAGE) {                                                               \
    _Pragma("unroll") for (int a_ = 0; a_ < 4; ++a_) {                          \
      ap[a_] += BK; bp[a_] += BK; }                                             \
  }                                                                             \
} while (0)

// ---------------- GEMM1 (fused shared+routed): A[M,1024] = swiglu(X @ Wgu^T) ----------------
// item = (mt<<4)|f0, f0 in 0..7. N-tile 256 = 128 gate + 128 up cols interleaved at
// 16-col granularity; inter cols f0*128 .. f0*128+127.
__global__ __launch_bounds__(512, 2) void gemm1_fused(
    const bf16_t* __restrict__ Xb, const bf16_t* __restrict__ WS,
    const bf16_t* __restrict__ WE, bf16_t* __restrict__ As, bf16_t* __restrict__ Ar,
    const int* __restrict__ row_token, const int* __restrict__ tileExpert,
    const int* __restrict__ work1) {
  const int item = work1[blockIdx.x];
  if (item < 0) return;
  const int mt = item >> 4;
  const int f0 = item & 15;

  const bf16_t* W; bf16_t* Aout; int m0; const int* rtok = nullptr;
  if (mt < SH_TILES) {
    m0 = mt * 256; W = WS; Aout = As;
  } else {
    int rt = mt - SH_TILES;
    m0 = rt * 256; W = WE + (size_t)tileExpert[rt] * (GUP * DMODEL);
    Aout = Ar; rtok = row_token;
  }

  __shared__ bf16_t sA[2][16384];   // 64KB
  __shared__ bf16_t sB[2][16384];   // 64KB

  const int tid = threadIdx.x;
  const int w = tid >> 6, lane = tid & 63;
  const int wm = w >> 2, wn = w & 3;
  const int lr = lane & 15, quad = lane >> 4;

  // staging pointers (pre-swizzled global sources; linear LDS dests)
  const bf16_t* ap[4]; const bf16_t* bp[4];
#pragma unroll
  for (int a = 0; a < 4; a++) {
    int row = a * 64 + (tid >> 3);
    int ch = (tid & 7) ^ (row & 7);
    int tok = m0 + row;
    if (rtok) { int tt = rtok[tok]; tok = (tt < 0) ? 0 : tt; }
    ap[a] = Xb + (size_t)tok * DMODEL + ch * 8;
    // B: LDS row Rl -> permuted n -> gate/up interleaved W row
    int h = (row >> 7) & 1, wnn = (row >> 5) & 3, rr = row & 31;
    int n = wnn * 64 + h * 32 + rr;
    int ni = n >> 4;
    int wrow = (ni & 1) * 1024 + f0 * 128 + (ni >> 1) * 16 + (n & 15);
    bp[a] = W + (size_t)wrow * DMODEL + ch * 8;
  }

  const int chA0 = (quad ^ (lr & 7)) * 8;
  const int chA1 = ((4 + quad) ^ (lr & 7)) * 8;
  const int rowA = (wm * 128 + lr) * 64;
  const int rowB = (wn * 32 + lr) * 64;

  f32x4 acc[8][4];
#pragma unroll
  for (int mi = 0; mi < 8; mi++)
#pragma unroll
    for (int ni = 0; ni < 4; ni++) acc[mi][ni] = (f32x4){0.f, 0.f, 0.f, 0.f};

  // prologue: stage K-tile 0 into slot 0 (A0,A1,A2,A3,B0,B1,B2,B3); force all but B1-half
#pragma unroll
  for (int a = 0; a < 4; a++) async16(ap[a], &sA[0][a * 4096 + w * 512]);
#pragma unroll
  for (int a = 0; a < 4; a++) async16(bp[a], &sB[0][a * 4096 + w * 512]);
#pragma unroll
  for (int a = 0; a < 4; a++) { ap[a] += BK; bp[a] += BK; }
  asm volatile("s_waitcnt vmcnt(2)" ::: "memory");
  __builtin_amdgcn_s_barrier();

#pragma unroll 1
  for (int it = 0; it < 7; ++it) {
    GROUP8(0, 1, true, 4, 2);
    GROUP8(1, 0, true, 4, 2);
  }
  GROUP8(0, 1, true, 4, 2);    // kt=14, stages tile 15
  GROUP8(1, 0, false, 0, 0);   // kt=15

  // epilogue: gate = acc[mi][nh*2+0], up = acc[mi][nh*2+1];
  // inter col block = f0*128 + (wn*2+nh)*16. Zero-padded weights give exact 0
  // for inter cols >= 938 (gemm2 runs K=1024 over these).
#pragma unroll
  for (int mi = 0; mi < 8; mi++)
#pragma unroll
    for (int nh = 0; nh < 2; nh++)
#pragma unroll
      for (int r = 0; r < 4; r++) {
        int row = m0 + wm * 128 + mi * 16 + quad * 4 + r;
        int col = f0 * 128 + (wn * 2 + nh) * 16 + lr;
        float g = acc[mi][nh * 2 + 0][r], u = acc[mi][nh * 2 + 1][r];
        float v = (g / (1.f + __expf(-g))) * u;
        Aout[(size_t)row * AP + col] = (bf16_t)v;
      }
}

// ---------------- GEMM2 (fused shared+routed): Out[M,1024] = A @ Wd^T, K=1024 ----------------
// item = (mt<<4)|f, f in 0..3, n0 = f*256.
__global__ __launch_bounds__(512, 2) void gemm2_fused(
    const bf16_t* __restrict__ As, const bf16_t* __restrict__ Ar,
    const bf16_t* __restrict__ WS, const bf16_t* __restrict__ WE,
    float* __restrict__ Out, bf16_t* __restrict__ Yr,
    const float* __restrict__ row_weight, const int* __restrict__ tileExpert,
    const int* __restrict__ work2) {
  const int item = work2[blockIdx.x];
  if (item < 0) return;
  const int mt = item >> 4;
  const int n0 = (item & 15) * 256;

  const bf16_t* A; const bf16_t* W; int m0; bool routed;
  if (mt < SH_TILES) {
    routed = false; m0 = mt * 256; A = As; W = WS;
  } else {
    int rt = mt - SH_TILES;
    routed = true; m0 = rt * 256; A = Ar;
    W = WE + (size_t)tileExpert[rt] * (DMODEL * AP);
  }

  __shared__ bf16_t sA[2][16384];
  __shared__ bf16_t sB[2][16384];

  const int tid = threadIdx.x;
  const int w = tid >> 6, lane = tid & 63;
  const int wm = w >> 2, wn = w & 3;
  const int lr = lane & 15, quad = lane >> 4;

  const bf16_t* ap[4]; const bf16_t* bp[4];
#pragma unroll
  for (int a = 0; a < 4; a++) {
    int row = a * 64 + (tid >> 3);
    int ch = (tid & 7) ^ (row & 7);
    ap[a] = A + (size_t)(m0 + row) * AP + ch * 8;
    int h = (row >> 7) & 1, wnn = (row >> 5) & 3, rr = row & 31;
    int n = wnn * 64 + h * 32 + rr;
    bp[a] = W + (size_t)(n0 + n) * AP + ch * 8;
  }

  const int chA0 = (quad ^ (lr & 7)) * 8;
  const int chA1 = ((4 + quad) ^ (lr & 7)) * 8;
  const int rowA = (wm * 128 + lr) * 64;
  const int rowB = (wn * 32 + lr) * 64;

  f32x4 acc[8][4];
#pragma unroll
  for (int mi = 0; mi < 8; mi++)
#pragma unroll
    for (int ni = 0; ni < 4; ni++) acc[mi][ni] = (f32x4){0.f, 0.f, 0.f, 0.f};

#pragma unroll
  for (int a = 0; a < 4; a++) async16(ap[a], &sA[0][a * 4096 + w * 512]);
#pragma unroll
  for (int a = 0; a < 4; a++) async16(bp[a], &sB[0][a * 4096 + w * 512]);
#pragma unroll
  for (int a = 0; a < 4; a++) { ap[a] += BK; bp[a] += BK; }
  asm volatile("s_waitcnt vmcnt(2)" ::: "memory");
  __builtin_amdgcn_s_barrier();

#pragma unroll 1
  for (int it = 0; it < 7; ++it) {
    GROUP8(0, 1, true, 4, 2);
    GROUP8(1, 0, true, 4, 2);
  }
  GROUP8(0, 1, true, 4, 2);
  GROUP8(1, 0, false, 0, 0);

#pragma unroll
  for (int mi = 0; mi < 8; mi++) {
#pragma unroll
    for (int r = 0; r < 4; r++) {
      int row = m0 + wm * 128 + mi * 16 + quad * 4 + r;
      float rw = routed ? row_weight[row] : 0.f;
#pragma unroll
      for (int nh = 0; nh < 2; nh++)
#pragma unroll
        for (int nf = 0; nf < 2; nf++) {
          int col = n0 + wn * 64 + nh * 32 + nf * 16 + lr;
          float v = acc[mi][nh * 2 + nf][r];
          if (!routed) Out[(size_t)row * DMODEL + col] = v;
          else         Yr[(size_t)row * DMODEL + col] = (bf16_t)(rw * v);
        }
    }
  }
}

// ---------------- combine: Out[t] += Yr[slot0(t)] + Yr[slot1(t)] ----------------
__global__ __launch_bounds__(256) void combine_kernel(
    float4* __restrict__ Out4, const ushort4* __restrict__ Yr4,
    const int* __restrict__ slotOf) {
  int t = blockIdx.x;
  int c = threadIdx.x;
  int s0 = slotOf[t * 2 + 0];
  int s1 = slotOf[t * 2 + 1];
  float4 o = Out4[t * 256 + c];
  ushort4 a = Yr4[(size_t)s0 * 256 + c];
  ushort4 b = Yr4[(size_t)s1 * 256 + c];
  union { unsigned int u; float f; } cv;
  auto b2f = [&](unsigned short x) { cv.u = ((unsigned int)x) << 16; return cv.f; };
  o.x += b2f(a.x) + b2f(b.x);
  o.y += b2f(a.y) + b2f(b.y);
  o.z += b2f(a.z) + b2f(b.z);
  o.w += b2f(a.w) + b2f(b.w);
  Out4[t * 256 + c] = o;
}

// ---------------- launch ----------------
extern "C" void kernel_launch(void* const* d_in, const int* in_sizes, int n_in,
                              void* d_out, int out_size, void* d_ws, size_t ws_size,
                              hipStream_t stream) {
  const float* X   = (const float*)d_in[0];
  const float* GW  = (const float*)d_in[1];
  const float* SGU = (const float*)d_in[2];
  const float* SD  = (const float*)d_in[3];
  const float* EGU = (const float*)d_in[4];
  const float* ED  = (const float*)d_in[5];
  float* Out = (float*)d_out;

  char* ws = (char*)d_ws;
  size_t o = 0;
  auto alloc = [&](size_t b) -> char* {
    char* p = ws + o;
    o = (o + b + 255) & ~(size_t)255;
    return p;
  };
  bf16_t* Xb    = (bf16_t*)alloc((size_t)TOKENS * DMODEL * 2);          // 16.8 MB
  bf16_t* WguSP = (bf16_t*)alloc((size_t)GUP * DMODEL * 2);             // 4.2 MB
  bf16_t* WdSP  = (bf16_t*)alloc((size_t)DMODEL * AP * 2);              // 2.1 MB
  bf16_t* WguEP = (bf16_t*)alloc((size_t)NEXP * GUP * DMODEL * 2);      // 33.6 MB
  bf16_t* WdEP  = (bf16_t*)alloc((size_t)NEXP * DMODEL * AP * 2);       // 16.8 MB
  bf16_t* As    = (bf16_t*)alloc((size_t)TOKENS * AP * 2);              // 16.8 MB
  bf16_t* Ar    = (bf16_t*)alloc((size_t)CAP_ROWS * AP * 2);            // 37.7 MB
  bf16_t* Yr    = (bf16_t*)alloc((size_t)CAP_ROWS * DMODEL * 2);        // 37.7 MB
  int*    e01    = (int*)alloc(TOKENS * 2 * 4);
  float*  w01    = (float*)alloc(TOKENS * 2 * 4);
  int*    slotOf = (int*)alloc(TOKENS * 2 * 4);
  int*    blkCnt = (int*)alloc(PLAN_BLOCKS * NEXP * 4);
  int*    blkBas = (int*)alloc(PLAN_BLOCKS * NEXP * 4);
  int*    tileEx = (int*)alloc(MAX_TILES * 4);
  int*    work1  = (int*)alloc(G1SLOTS * 4);
  int*    work2  = (int*)alloc(G2SLOTS * 4);
  int*    rowTok = (int*)alloc(CAP_ROWS * 4);
  float*  rowW   = (float*)alloc(CAP_ROWS * 4);
  (void)ws_size; (void)in_sizes; (void)n_in; (void)out_size;

  // weight re-layout (padded)
  conv_gu_pad<<<2048, 256, 0, stream>>>((const float4*)SGU, (ushort4*)WguSP);
  conv_gu_pad<<<NEXP * 2048, 256, 0, stream>>>((const float4*)EGU, (ushort4*)WguEP);
  conv_dn_pad<<<4096, 256, 0, stream>>>(SD, WdSP);
  conv_dn_pad<<<NEXP * 4096, 256, 0, stream>>>(ED, WdEP);

  // routing
  init_kernel<<<(CAP_ROWS + 255) / 256, 256, 0, stream>>>(rowTok);
  router_kernel<<<TOKENS / 4, 256, 0, stream>>>(
      (const float4*)X, (const float4*)GW, Xb, e01, w01);
  hist_kernel<<<PLAN_BLOCKS, 256, 0, stream>>>(e01, blkCnt);
  plan_kernel<<<1, 256, 0, stream>>>(blkCnt, blkBas, tileEx, work1, work2);
  scatter_kernel<<<PLAN_BLOCKS, 256, 0, stream>>>(e01, w01, blkBas, rowTok, rowW, slotOf);

  // GEMMs: 256^2 8-phase pipelined, work-list driven with expert<->XCD affinity
  gemm1_fused<<<G1SLOTS, 512, 0, stream>>>(
      Xb, WguSP, WguEP, As, Ar, rowTok, tileEx, work1);
  gemm2_fused<<<G2SLOTS, 512, 0, stream>>>(
      As, Ar, WdSP, WdEP, Out, Yr, rowW, tileEx, work2);
  combine_kernel<<<TOKENS, 256, 0, stream>>>((float4*)Out, (const ushort4*)Yr, slotOf);
}

// Round 4
// 407.797 us; speedup vs baseline: 1.0847x; 1.0720x over previous
//
#include <hip/hip_runtime.h>
#include <hip/hip_bf16.h>
#include <stdint.h>

// MoE: B=4,S=2048,D=1024,E=8,TOPK=2,I=938. Sparse top-2 routing + bf16 MFMA GEMMs.
// R10: occupancy lever. 128x256 tile, BK=32, 8 waves (wave-tile 64x64, acc[4][4]),
//      triple-buffered 72KB LDS, <=128 VGPR via __launch_bounds__(512,4) ->
//      2 blocks/CU (16 waves). Per K-tile: {stage 3 gloads for t+2 -> 8 ds_read ->
//      16 MFMA -> vmcnt(3) (forces t+1, staged ~2 tiles ago) -> 1 barrier}.
//      Cross-block drift provides the LDS/MFMA overlap no intra-block schedule gave
//      (R7/R8/R9 all 26-35% MfmaUtil at 1 block/CU). Swizzle: chunk^(row+(row>>2))&3.

typedef __bf16 bf16_t;
typedef __bf16 bf16x8 __attribute__((ext_vector_type(8)));
typedef float  f32x4  __attribute__((ext_vector_type(4)));

#define TOKENS    8192
#define DMODEL    1024
#define NEXP      8
#define INTER     938
#define AP        1024     // padded inter dim (A cols / gemm2 K / Wd cols)
#define GUP       2048     // padded gate(1024)+up(1024) rows per expert
#define CAP_ROWS  17408    // 16384 + 8*128
#define MAX_TILES 144
#define SH_TILES  64       // 8192/128 shared M-tiles
#define BK        32
#define NT        32       // K-tiles = 1024/32
#define SLOT      12288    // LDS slot elements (24KB): A[128x32]=4096 | B[256x32]=8192

#define G1SLOTS   2048     // 8 residues x 256 ranks
#define G1PER     256
#define G2SLOTS   1024     // 8 residues x 128 ranks
#define G2PER     128

#define PLAN_BLOCKS 16
#define TOK_PER_PLAN (TOKENS / PLAN_BLOCKS)

// ---- async global->LDS, 16B per lane; LDS dest = wave-uniform base + lane*16 ----
__device__ __forceinline__ void async16(const bf16_t* g, bf16_t* l) {
  __builtin_amdgcn_global_load_lds(
      (__attribute__((address_space(1))) void*)(g),
      (__attribute__((address_space(3))) void*)(l),
      16, 0, 0);
}

__device__ __forceinline__ unsigned short f2bu(float f) {
  bf16_t b = (bf16_t)f;
  unsigned short u;
  __builtin_memcpy(&u, &b, 2);
  return u;
}

// ---------------- weight re-layout converts ----------------
__global__ void conv_gu_pad(const float4* __restrict__ src, ushort4* __restrict__ dst) {
  int i = blockIdx.x * 256 + threadIdx.x;
  int e = i >> 19;            // GUP*256 = 2^19
  int rem = i & 524287;
  int r = rem >> 8;
  int c4 = rem & 255;
  const float4* s = src + (size_t)e * (1876 * 256);
  float4 v = {0.f, 0.f, 0.f, 0.f};
  if (r < INTER) v = s[r * 256 + c4];
  else if (r >= 1024 && r < 1024 + INTER) v = s[(r - 86) * 256 + c4];
  ushort4 o;
  o.x = f2bu(v.x); o.y = f2bu(v.y); o.z = f2bu(v.z); o.w = f2bu(v.w);
  dst[i] = o;
}

__global__ void conv_dn_pad(const float* __restrict__ src, bf16_t* __restrict__ dst) {
  int i = blockIdx.x * 256 + threadIdx.x;
  int e = i >> 20;
  int rem = i & 1048575;
  int n = rem >> 10;
  int c = rem & 1023;
  float v = (c < INTER) ? src[(size_t)e * (1024 * INTER) + n * INTER + c] : 0.f;
  dst[i] = (bf16_t)v;
}

// ---------------- routing ----------------
__global__ void init_kernel(int* __restrict__ row_token) {
  int i = blockIdx.x * 256 + threadIdx.x;
  if (i < CAP_ROWS) row_token[i] = -1;
}

__global__ __launch_bounds__(256) void router_kernel(
    const float4* __restrict__ X4, const float4* __restrict__ GW4,
    bf16_t* __restrict__ Xb, int* __restrict__ e01, float* __restrict__ w01) {
  int token = blockIdx.x * 4 + (threadIdx.x >> 6);
  int lane = threadIdx.x & 63;
  const float4* x4 = X4 + (size_t)token * 256;

  float4 xv[4];
#pragma unroll
  for (int j = 0; j < 4; j++) xv[j] = x4[lane + 64 * j];

  ushort4* xbrow = (ushort4*)(Xb + (size_t)token * DMODEL);
#pragma unroll
  for (int j = 0; j < 4; j++) {
    ushort4 r;
    r.x = f2bu(xv[j].x); r.y = f2bu(xv[j].y);
    r.z = f2bu(xv[j].z); r.w = f2bu(xv[j].w);
    xbrow[lane + 64 * j] = r;
  }

  float acc[NEXP];
#pragma unroll
  for (int e = 0; e < NEXP; e++) {
    float a = 0.f;
#pragma unroll
    for (int j = 0; j < 4; j++) {
      float4 g = GW4[e * 256 + lane + 64 * j];
      a += xv[j].x * g.x + xv[j].y * g.y + xv[j].z * g.z + xv[j].w * g.w;
    }
    acc[e] = a;
  }
#pragma unroll
  for (int off = 32; off > 0; off >>= 1)
#pragma unroll
    for (int e = 0; e < NEXP; e++) acc[e] += __shfl_down(acc[e], off, 64);

  if (lane == 0) {
    float mx = acc[0];
#pragma unroll
    for (int e = 1; e < NEXP; e++) mx = fmaxf(mx, acc[e]);
    float p[NEXP]; float s = 0.f;
#pragma unroll
    for (int e = 0; e < NEXP; e++) { p[e] = expf(acc[e] - mx); s += p[e]; }
    int i0 = 0;
#pragma unroll
    for (int e = 1; e < NEXP; e++) if (p[e] > p[i0]) i0 = e;
    int i1 = (i0 == 0) ? 1 : 0;
#pragma unroll
    for (int e = 0; e < NEXP; e++) if (e != i1 && e != i0 && p[e] > p[i1]) i1 = e;
    float p0 = p[i0] / s, p1 = p[i1] / s;
    float inv = 1.f / (p0 + p1 + 1e-8f);
    e01[token * 2 + 0] = i0; e01[token * 2 + 1] = i1;
    w01[token * 2 + 0] = p0 * inv; w01[token * 2 + 1] = p1 * inv;
  }
}

__global__ void hist_kernel(const int* __restrict__ e01, int* __restrict__ blockCounts) {
  __shared__ int h[NEXP];
  int t = threadIdx.x;
  if (t < NEXP) h[t] = 0;
  __syncthreads();
  int base = blockIdx.x * TOK_PER_PLAN * 2;
  for (int i = t; i < TOK_PER_PLAN * 2; i += 256) atomicAdd(&h[e01[base + i]], 1);
  __syncthreads();
  if (t < NEXP) blockCounts[blockIdx.x * NEXP + t] = h[t];
}

// ---------------- plan: blockBase, tileExpert, XCD-affine work lists ----------------
// 128-row tiles. gemm1: 8 f-blocks per mt (128 inter cols each).
// gemm2: 4 f-blocks per mt (256 out cols each).
__global__ __launch_bounds__(256) void plan_kernel(
    const int* __restrict__ blockCounts, int* __restrict__ blockBase,
    int* __restrict__ tileExpert, int* __restrict__ work1, int* __restrict__ work2) {
  __shared__ int cnt[8], tc[8], tb[8], n1[8], n2[8];
  __shared__ int f1n, f2n, f1c, f2c;
  __shared__ short free1[G1SLOTS];
  __shared__ short free2[G2SLOTS];
  const int t = threadIdx.x;

  if (t < 8) {
    int s = 0;
    for (int b = 0; b < PLAN_BLOCKS; b++) s += blockCounts[b * 8 + t];
    cnt[t] = s;
  }
  if (t == 0) { f1n = 0; f2n = 0; f1c = 0; f2c = 0; }
  __syncthreads();
  if (t == 0) {
    int o = 0;
    for (int e = 0; e < 8; e++) {
      tb[e] = o;
      tc[e] = (cnt[e] + 127) / 128;
      o += tc[e];
    }
    for (int s = 0; s < 8; s++) { n1[s] = 64 + 8 * tc[s]; n2[s] = 32 + 4 * tc[s]; }
  }
  __syncthreads();
  const int nT = tb[7] + tc[7];

  if (t < 8) {            // blockBase for scatter (rows)
    int run = tb[t] * 128;
    for (int b = 0; b < PLAN_BLOCKS; b++) {
      blockBase[b * 8 + t] = run;
      run += blockCounts[b * 8 + t];
    }
  }
  for (int i = t; i < MAX_TILES; i += 256) {   // tileExpert (128-row routed tiles)
    int e = 0;
#pragma unroll
    for (int x = 1; x < 8; x++) if (i >= tb[x]) e = x;
    tileExpert[i] = e;
  }
  for (int i = t; i < G1SLOTS; i += 256) work1[i] = -1;
  for (int i = t; i < G2SLOTS; i += 256) work2[i] = -1;
  __syncthreads();

  // own-rank fills. gemm1 shared: mt 0..63, f 0..7 -> residue mt&7, rank (mt>>3)*8+f
  for (int i = t; i < 512; i += 256) {
    int mt = i >> 3, f = i & 7;
    work1[(mt & 7) + 8 * ((mt >> 3) * 8 + f)] = (mt << 4) | f;
  }
  for (int i = t; i < 8 * nT; i += 256) {      // gemm1 routed: residue = expert
    int tt = i >> 3, f = i & 7;
    int e = 0;
#pragma unroll
    for (int x = 1; x < 8; x++) if (tt >= tb[x]) e = x;
    int rk = 64 + (tt - tb[e]) * 8 + f;
    if (rk < G1PER) work1[e + 8 * rk] = ((SH_TILES + tt) << 4) | f;
  }
  for (int i = t; i < 256; i += 256) {         // gemm2 shared: mt 0..63, f 0..3
    int mt = i >> 2, f = i & 3;
    work2[(mt & 7) + 8 * ((mt >> 3) * 4 + f)] = (mt << 4) | f;
  }
  for (int i = t; i < 4 * nT; i += 256) {      // gemm2 routed
    int tt = i >> 2, f = i & 3;
    int e = 0;
#pragma unroll
    for (int x = 1; x < 8; x++) if (tt >= tb[x]) e = x;
    int rk = 32 + (tt - tb[e]) * 4 + f;
    if (rk < G2PER) work2[e + 8 * rk] = ((SH_TILES + tt) << 4) | f;
  }
  __syncthreads();

  // free slots (residues whose own list is short)
  for (int i = t; i < G1SLOTS; i += 256)
    if ((i >> 3) >= n1[i & 7]) free1[atomicAdd(&f1n, 1)] = (short)i;
  for (int i = t; i < G2SLOTS; i += 256)
    if ((i >> 3) >= n2[i & 7]) free2[atomicAdd(&f2n, 1)] = (short)i;
  __syncthreads();

  // overflow items (imbalanced experts) -> spill into free slots
  for (int i = t; i < 8 * nT; i += 256) {
    int tt = i >> 3, f = i & 7;
    int e = 0;
#pragma unroll
    for (int x = 1; x < 8; x++) if (tt >= tb[x]) e = x;
    int rk = 64 + (tt - tb[e]) * 8 + f;
    if (rk >= G1PER) work1[free1[atomicAdd(&f1c, 1)]] = ((SH_TILES + tt) << 4) | f;
  }
  for (int i = t; i < 4 * nT; i += 256) {
    int tt = i >> 2, f = i & 3;
    int e = 0;
#pragma unroll
    for (int x = 1; x < 8; x++) if (tt >= tb[x]) e = x;
    int rk = 32 + (tt - tb[e]) * 4 + f;
    if (rk >= G2PER) work2[free2[atomicAdd(&f2c, 1)]] = ((SH_TILES + tt) << 4) | f;
  }
}

// block-local ranks via LDS atomics; emits slotOf (token -> its 2 slot rows)
__global__ void scatter_kernel(const int* __restrict__ e01, const float* __restrict__ w01,
                               const int* __restrict__ blockBase,
                               int* __restrict__ row_token, float* __restrict__ row_weight,
                               int* __restrict__ slotOf) {
  __shared__ int cur[NEXP];
  __shared__ int base[NEXP];
  int t = threadIdx.x;
  if (t < NEXP) { cur[t] = 0; base[t] = blockBase[blockIdx.x * NEXP + t]; }
  __syncthreads();
  int tb = blockIdx.x * TOK_PER_PLAN;
  for (int i = t; i < TOK_PER_PLAN * 2; i += 256) {
    int e = e01[tb * 2 + i];
    int rank = atomicAdd(&cur[e], 1);
    int pos = base[e] + rank;
    row_token[pos] = tb + (i >> 1);
    row_weight[pos] = w01[tb * 2 + i];
    slotOf[tb * 2 + i] = pos;
  }
}

// ================= 128x256 / BK=32 / 3-slot GEMM core =================
// 512 thr = 8 waves (2M x 4N): wave-tile 64x64, acc[4][4]. LDS slot 24KB
// (A 128x32 | B 256x32), 3 slots = 72KB -> 2 blocks/CU at VGPR<=128.
// Per K-tile t (read slot t%3, stage t+2 -> slot (t+2)%3):
//   {3 gloads for t+2 -> 8 ds_read -> setprio(1) 16 MFMA setprio(0) ->
//    vmcnt(3) [forces t+1's 3 loads, issued during t-1: ~2 K-tiles old] -> barrier}
// One barrier per K-tile. Swizzle: 16B chunk c stored at c ^ ((row+(row>>2))&3);
// invariant mod 4 across mi*16/ni*16/w*16 strides -> fragment reads are base+imm,
// 2 lanes/bank max on ds_read (free). Staged via pre-swizzled per-lane global src.

#define KLOOP_BODY(STAGE3)                                                      \
  f32x4 acc[4][4];                                                              \
  _Pragma("unroll") for (int mi = 0; mi < 4; ++mi)                              \
  _Pragma("unroll") for (int ni = 0; ni < 4; ++ni)                              \
    acc[mi][ni] = (f32x4){0.f, 0.f, 0.f, 0.f};                                  \
  /* prologue: stage tiles 0,1 */                                               \
  STAGE3(0);                                                                    \
  apA += BK; bp0 += BK; bp1 += BK;                                              \
  STAGE3(SLOT);                                                                 \
  apA += BK; bp0 += BK; bp1 += BK;                                              \
  asm volatile("s_waitcnt vmcnt(3)" ::: "memory");                              \
  __builtin_amdgcn_s_barrier();                                                 \
  int sOff = 0, dOff = 2 * SLOT;                                                \
  _Pragma("unroll 1")                                                           \
  for (int t = 0; t < NT; ++t) {                                                \
    if (t < NT - 2) {                                                           \
      STAGE3(dOff);                                                             \
      apA += BK; bp0 += BK; bp1 += BK;                                          \
    }                                                                           \
    bf16x8 av[4], bv[4];                                                        \
    const int aB = sOff + aBaseC, bB = sOff + bBaseC;                           \
    _Pragma("unroll") for (int mi = 0; mi < 4; ++mi)                            \
      av[mi] = *(const bf16x8*)&lds[aB + mi * 512];                             \
    _Pragma("unroll") for (int ni = 0; ni < 4; ++ni)                            \
      bv[ni] = *(const bf16x8*)&lds[bB + ni * 512];                             \
    __builtin_amdgcn_s_setprio(1);                                              \
    _Pragma("unroll") for (int mi = 0; mi < 4; ++mi)                            \
    _Pragma("unroll") for (int ni = 0; ni < 4; ++ni)                            \
      acc[mi][ni] = __builtin_amdgcn_mfma_f32_16x16x32_bf16(                    \
          av[mi], bv[ni], acc[mi][ni], 0, 0, 0);                                \
    __builtin_amdgcn_s_setprio(0);                                              \
    if (t < NT - 2) {                                                           \
      asm volatile("s_waitcnt vmcnt(3)" ::: "memory");                          \
      __builtin_amdgcn_s_barrier();                                             \
    } else if (t == NT - 2) {                                                   \
      asm volatile("s_waitcnt vmcnt(0)" ::: "memory");                          \
      __builtin_amdgcn_s_barrier();                                             \
    }                                                                           \
    sOff += SLOT; if (sOff == 3 * SLOT) sOff = 0;                               \
    dOff += SLOT; if (dOff == 3 * SLOT) dOff = 0;                               \
  }

// ---------------- GEMM1 (fused shared+routed): A[M,1024] = swiglu(X @ Wgu^T) ----------------
// item = (mt<<4)|f0, f0 0..7. N-tile 256 = 128 gate + 128 up interleaved at 16-col
// granularity (pairs in-wave); inter cols f0*128..f0*128+127. Writes all 1024 padded
// A cols (pad cols exact 0 from zero weights) so gemm2 runs K=1024.
__global__ __launch_bounds__(512, 4) void gemm1_fused(
    const bf16_t* __restrict__ Xb, const bf16_t* __restrict__ WS,
    const bf16_t* __restrict__ WE, bf16_t* __restrict__ As, bf16_t* __restrict__ Ar,
    const int* __restrict__ row_token, const int* __restrict__ tileExpert,
    const int* __restrict__ work1) {
  const int item = work1[blockIdx.x];
  if (item < 0) return;
  const int mt = item >> 4;
  const int f0 = item & 15;

  const bf16_t* W; bf16_t* Aout; int m0; const int* rtok = nullptr;
  if (mt < SH_TILES) {
    m0 = mt * 128; W = WS; Aout = As;
  } else {
    int rt = mt - SH_TILES;
    m0 = rt * 128; W = WE + (size_t)tileExpert[rt] * (GUP * DMODEL);
    Aout = Ar; rtok = row_token;
  }

  __shared__ bf16_t lds[3 * SLOT];   // 72KB

  const int tid = threadIdx.x;
  const int w = tid >> 6, lane = tid & 63;
  const int wm = w >> 2, wn = w & 3;
  const int lr = lane & 15, quad = lane >> 4;

  // staging sources: lane -> (row = w*16 + lane>>2, chunk = (lane&3) ^ swz(row))
  const int arow = w * 16 + (lane >> 2);
  const int srcch = ((lane & 3) ^ (((lane >> 2) + (lane >> 4)) & 3)) * 8;
  int tokA = m0 + arow;
  if (rtok) { int tt = rtok[tokA]; tokA = (tt < 0) ? 0 : tt; }
  const bf16_t* apA = Xb + (size_t)tokA * DMODEL + srcch;
  const bf16_t* bp0; const bf16_t* bp1;
  {
    int n = arow;                         // B gload 0: n rows 0..127
    int ni = n >> 4;
    int wr = (ni & 1) * 1024 + f0 * 128 + (ni >> 1) * 16 + (n & 15);
    bp0 = W + (size_t)wr * DMODEL + srcch;
    n = 128 + arow;                       // B gload 1: n rows 128..255
    ni = n >> 4;
    wr = (ni & 1) * 1024 + f0 * 128 + (ni >> 1) * 16 + (n & 15);
    bp1 = W + (size_t)wr * DMODEL + srcch;
  }

  // fragment read bases (chunk term invariant across mi/ni: strides = 0 mod 4)
  const int chA = (quad ^ ((lr + (lr >> 2)) & 3)) * 8;
  const int aBaseC = (wm * 64 + lr) * 32 + chA;
  const int bBaseC = 4096 + (wn * 64 + lr) * 32 + chA;

#define STAGE3_G1(D)                                                            \
  do {                                                                          \
    async16(apA, &lds[(D) + w * 512]);                                          \
    async16(bp0, &lds[(D) + 4096 + w * 512]);                                   \
    async16(bp1, &lds[(D) + 8192 + w * 512]);                                   \
  } while (0)

  KLOOP_BODY(STAGE3_G1)

  // epilogue: gate = acc[mi][2j], up = acc[mi][2j+1]; col = f0*128 + (wn*2+j)*16 + lr
#pragma unroll
  for (int mi = 0; mi < 4; mi++)
#pragma unroll
    for (int j = 0; j < 2; j++)
#pragma unroll
      for (int r = 0; r < 4; r++) {
        int row = m0 + wm * 64 + mi * 16 + quad * 4 + r;
        int col = f0 * 128 + (wn * 2 + j) * 16 + lr;
        float g = acc[mi][2 * j][r], u = acc[mi][2 * j + 1][r];
        float v = (g / (1.f + __expf(-g))) * u;
        Aout[(size_t)row * AP + col] = (bf16_t)v;
      }
}

// ---------------- GEMM2 (fused shared+routed): Out[M,1024] = A @ Wd^T, K=1024 ----------------
// item = (mt<<4)|f, f 0..3, n0 = f*256.
__global__ __launch_bounds__(512, 4) void gemm2_fused(
    const bf16_t* __restrict__ As, const bf16_t* __restrict__ Ar,
    const bf16_t* __restrict__ WS, const bf16_t* __restrict__ WE,
    float* __restrict__ Out, bf16_t* __restrict__ Yr,
    const float* __restrict__ row_weight, const int* __restrict__ tileExpert,
    const int* __restrict__ work2) {
  const int item = work2[blockIdx.x];
  if (item < 0) return;
  const int mt = item >> 4;
  const int n0 = (item & 15) * 256;

  const bf16_t* A; const bf16_t* W; int m0; bool routed;
  if (mt < SH_TILES) {
    routed = false; m0 = mt * 128; A = As; W = WS;
  } else {
    int rt = mt - SH_TILES;
    routed = true; m0 = rt * 128; A = Ar;
    W = WE + (size_t)tileExpert[rt] * (DMODEL * AP);
  }

  __shared__ bf16_t lds[3 * SLOT];

  const int tid = threadIdx.x;
  const int w = tid >> 6, lane = tid & 63;
  const int wm = w >> 2, wn = w & 3;
  const int lr = lane & 15, quad = lane >> 4;

  const int arow = w * 16 + (lane >> 2);
  const int srcch = ((lane & 3) ^ (((lane >> 2) + (lane >> 4)) & 3)) * 8;
  const bf16_t* apA = A + (size_t)(m0 + arow) * AP + srcch;
  const bf16_t* bp0 = W + (size_t)(n0 + arow) * AP + srcch;
  const bf16_t* bp1 = W + (size_t)(n0 + 128 + arow) * AP + srcch;

  const int chA = (quad ^ ((lr + (lr >> 2)) & 3)) * 8;
  const int aBaseC = (wm * 64 + lr) * 32 + chA;
  const int bBaseC = 4096 + (wn * 64 + lr) * 32 + chA;

#define STAGE3_G2(D)                                                            \
  do {                                                                          \
    async16(apA, &lds[(D) + w * 512]);                                          \
    async16(bp0, &lds[(D) + 4096 + w * 512]);                                   \
    async16(bp1, &lds[(D) + 8192 + w * 512]);                                   \
  } while (0)

  KLOOP_BODY(STAGE3_G2)

#pragma unroll
  for (int mi = 0; mi < 4; mi++) {
#pragma unroll
    for (int r = 0; r < 4; r++) {
      int row = m0 + wm * 64 + mi * 16 + quad * 4 + r;
      float rw = routed ? row_weight[row] : 0.f;
#pragma unroll
      for (int ni = 0; ni < 4; ni++) {
        int col = n0 + wn * 64 + ni * 16 + lr;
        float v = acc[mi][ni][r];
        if (!routed) Out[(size_t)row * DMODEL + col] = v;
        else         Yr[(size_t)row * DMODEL + col] = (bf16_t)(rw * v);
      }
    }
  }
}

// ---------------- combine: Out[t] += Yr[slot0(t)] + Yr[slot1(t)] ----------------
__global__ __launch_bounds__(256) void combine_kernel(
    float4* __restrict__ Out4, const ushort4* __restrict__ Yr4,
    const int* __restrict__ slotOf) {
  int t = blockIdx.x;
  int c = threadIdx.x;
  int s0 = slotOf[t * 2 + 0];
  int s1 = slotOf[t * 2 + 1];
  float4 o = Out4[t * 256 + c];
  ushort4 a = Yr4[(size_t)s0 * 256 + c];
  ushort4 b = Yr4[(size_t)s1 * 256 + c];
  union { unsigned int u; float f; } cv;
  auto b2f = [&](unsigned short x) { cv.u = ((unsigned int)x) << 16; return cv.f; };
  o.x += b2f(a.x) + b2f(b.x);
  o.y += b2f(a.y) + b2f(b.y);
  o.z += b2f(a.z) + b2f(b.z);
  o.w += b2f(a.w) + b2f(b.w);
  Out4[t * 256 + c] = o;
}

// ---------------- launch ----------------
extern "C" void kernel_launch(void* const* d_in, const int* in_sizes, int n_in,
                              void* d_out, int out_size, void* d_ws, size_t ws_size,
                              hipStream_t stream) {
  const float* X   = (const float*)d_in[0];
  const float* GW  = (const float*)d_in[1];
  const float* SGU = (const float*)d_in[2];
  const float* SD  = (const float*)d_in[3];
  const float* EGU = (const float*)d_in[4];
  const float* ED  = (const float*)d_in[5];
  float* Out = (float*)d_out;

  char* ws = (char*)d_ws;
  size_t o = 0;
  auto alloc = [&](size_t b) -> char* {
    char* p = ws + o;
    o = (o + b + 255) & ~(size_t)255;
    return p;
  };
  bf16_t* Xb    = (bf16_t*)alloc((size_t)TOKENS * DMODEL * 2);          // 16.8 MB
  bf16_t* WguSP = (bf16_t*)alloc((size_t)GUP * DMODEL * 2);             // 4.2 MB
  bf16_t* WdSP  = (bf16_t*)alloc((size_t)DMODEL * AP * 2);              // 2.1 MB
  bf16_t* WguEP = (bf16_t*)alloc((size_t)NEXP * GUP * DMODEL * 2);      // 33.6 MB
  bf16_t* WdEP  = (bf16_t*)alloc((size_t)NEXP * DMODEL * AP * 2);       // 16.8 MB
  bf16_t* As    = (bf16_t*)alloc((size_t)TOKENS * AP * 2);              // 16.8 MB
  bf16_t* Ar    = (bf16_t*)alloc((size_t)CAP_ROWS * AP * 2);            // 35.7 MB
  bf16_t* Yr    = (bf16_t*)alloc((size_t)CAP_ROWS * DMODEL * 2);        // 35.7 MB
  int*    e01    = (int*)alloc(TOKENS * 2 * 4);
  float*  w01    = (float*)alloc(TOKENS * 2 * 4);
  int*    slotOf = (int*)alloc(TOKENS * 2 * 4);
  int*    blkCnt = (int*)alloc(PLAN_BLOCKS * NEXP * 4);
  int*    blkBas = (int*)alloc(PLAN_BLOCKS * NEXP * 4);
  int*    tileEx = (int*)alloc(MAX_TILES * 4);
  int*    work1  = (int*)alloc(G1SLOTS * 4);
  int*    work2  = (int*)alloc(G2SLOTS * 4);
  int*    rowTok = (int*)alloc(CAP_ROWS * 4);
  float*  rowW   = (float*)alloc(CAP_ROWS * 4);
  (void)ws_size; (void)in_sizes; (void)n_in; (void)out_size;

  // weight re-layout (padded)
  conv_gu_pad<<<2048, 256, 0, stream>>>((const float4*)SGU, (ushort4*)WguSP);
  conv_gu_pad<<<NEXP * 2048, 256, 0, stream>>>((const float4*)EGU, (ushort4*)WguEP);
  conv_dn_pad<<<4096, 256, 0, stream>>>(SD, WdSP);
  conv_dn_pad<<<NEXP * 4096, 256, 0, stream>>>(ED, WdEP);

  // routing
  init_kernel<<<(CAP_ROWS + 255) / 256, 256, 0, stream>>>(rowTok);
  router_kernel<<<TOKENS / 4, 256, 0, stream>>>(
      (const float4*)X, (const float4*)GW, Xb, e01, w01);
  hist_kernel<<<PLAN_BLOCKS, 256, 0, stream>>>(e01, blkCnt);
  plan_kernel<<<1, 256, 0, stream>>>(blkCnt, blkBas, tileEx, work1, work2);
  scatter_kernel<<<PLAN_BLOCKS, 256, 0, stream>>>(e01, w01, blkBas, rowTok, rowW, slotOf);

  // GEMMs: 128x256 / BK=32 / 3-slot pipelined, 2 blocks/CU, XCD-affine work lists
  gemm1_fused<<<G1SLOTS, 512, 0, stream>>>(
      Xb, WguSP, WguEP, As, Ar, rowTok, tileEx, work1);
  gemm2_fused<<<G2SLOTS, 512, 0, stream>>>(
      As, Ar, WdSP, WdEP, Out, Yr, rowW, tileEx, work2);
  combine_kernel<<<TOKENS, 256, 0, stream>>>((float4*)Out, (const ushort4*)Yr, slotOf);
}